// Round 4
// baseline (342.250 us; speedup 1.0000x reference)
//
#include <hip/hip_runtime.h>
#include <cstddef>

#define N_NODES  50000
#define N_EDGES  600000
#define N_FEAT   128
#define N_GRAPHS 256
#define DIMM     95
#define N_OUTD   12
#define N_ITERS  10

#define N_CHUNKS 196          // ceil(50000/256)

// workspace layout (float-element offsets; int arrays reinterpret the region)
#define WS_BUF   0                        // [50000*128] x1
#define WS_STATS (N_NODES * N_FEAT)       // [256] colsum[128], colsumsq[128]
#define WS_SCALE (WS_STATS + 256)         // [256] scale[128], shift[128]
#define WS_XG    (WS_SCALE + 256)         // [256*128]
#define WS_CNT   (WS_XG + N_GRAPHS * N_FEAT)   // int[50000] per-node degree
#define WS_OFF   (WS_CNT + N_NODES)            // int[50001] CSR offsets (pad 50004)
#define WS_CUR   (WS_OFF + N_NODES + 4)        // int[50000] scatter cursors
#define WS_CHS   (WS_CUR + N_NODES)            // int[256] chunk sums
#define WS_SORT  (WS_CHS + 256)                // int[600000] src sorted by dst

#define SR 132   // padded LDS row stride (128+4)

// ---- zero degree counters + BN stats ---------------------------------------
__global__ void k_zero(float* __restrict__ ws) {
    int i = blockIdx.x * 256 + threadIdx.x;
    int* cnt = (int*)ws + WS_CNT;
    if (i < N_NODES) cnt[i] = 0;
    if (blockIdx.x == 0) ws[WS_STATS + threadIdx.x] = 0.f;
}

// ---- degree histogram ------------------------------------------------------
__global__ void k_hist(const int* __restrict__ ei, float* __restrict__ ws) {
    int e = blockIdx.x * 256 + threadIdx.x;
    int* cnt = (int*)ws + WS_CNT;
    if (e < N_EDGES) atomicAdd(&cnt[ei[N_EDGES + e]], 1);
}

// ---- per-chunk sums (chunk = 256 nodes) ------------------------------------
__global__ void k_chunk(float* __restrict__ ws) {
    __shared__ int red[4];
    const int tid = threadIdx.x;
    int* cnt = (int*)ws + WS_CNT;
    int i = blockIdx.x * 256 + tid;
    int v = (i < N_NODES) ? cnt[i] : 0;
    #pragma unroll
    for (int d = 32; d; d >>= 1) v += __shfl_down(v, d);
    if ((tid & 63) == 0) red[tid >> 6] = v;
    __syncthreads();
    if (tid == 0) ((int*)ws + WS_CHS)[blockIdx.x] = red[0] + red[1] + red[2] + red[3];
}

// ---- exclusive scan of the (<=256) chunk sums, single block ----------------
__global__ void k_scan0(float* __restrict__ ws) {
    __shared__ int s[256];
    const int tid = threadIdx.x;
    int* chs = (int*)ws + WS_CHS;
    int v = (tid < N_CHUNKS) ? chs[tid] : 0;
    s[tid] = v;
    __syncthreads();
    #pragma unroll
    for (int d = 1; d < 256; d <<= 1) {
        int t = (tid >= d) ? s[tid - d] : 0;
        __syncthreads();
        s[tid] += t;
        __syncthreads();
    }
    if (tid < N_CHUNKS) chs[tid] = s[tid] - v;            // exclusive
    if (tid == 0) ((int*)ws + WS_OFF)[N_NODES] = N_EDGES; // sentinel
}

// ---- per-chunk exclusive scan -> CSR offsets + cursor copy -----------------
__global__ void k_scan1(float* __restrict__ ws) {
    __shared__ int s[256];
    const int tid = threadIdx.x;
    int* cnt = (int*)ws + WS_CNT;
    int* off = (int*)ws + WS_OFF;
    int* cur = (int*)ws + WS_CUR;
    int i = blockIdx.x * 256 + tid;
    int v = (i < N_NODES) ? cnt[i] : 0;
    s[tid] = v;
    __syncthreads();
    #pragma unroll
    for (int d = 1; d < 256; d <<= 1) {
        int t = (tid >= d) ? s[tid - d] : 0;
        __syncthreads();
        s[tid] += t;
        __syncthreads();
    }
    int o = ((int*)ws + WS_CHS)[blockIdx.x] + s[tid] - v;
    if (i < N_NODES) { off[i] = o; cur[i] = o; }
}

// ---- scatter: sortedSrc[pos in dst segment] = src --------------------------
__global__ void k_scatter(const int* __restrict__ ei, float* __restrict__ ws) {
    int e = blockIdx.x * 256 + threadIdx.x;
    if (e >= N_EDGES) return;
    int d = ei[N_EDGES + e];
    int s = ei[e];
    int* cur = (int*)ws + WS_CUR;
    int pos = atomicAdd(&cur[d], 1);
    ((int*)ws + WS_SORT)[pos] = s;
}

// ---- fused: CSR gather (h0 = x + agg, into LDS) + 2-layer MLP --------------
// LDS: single 64xSR tile reused for h0 (layer-1 input) and relu1 (layer-2
// input); layer-1 outputs live in registers across the barrier. 33.8 KB ->
// 4 blocks/CU.
__global__ __launch_bounds__(256, 4) void k_fused(const float* __restrict__ x,
        float* __restrict__ ws,
        const float* __restrict__ W1a, const float* __restrict__ b1a,
        const float* __restrict__ W1b, const float* __restrict__ b1b) {
    __shared__ float As[64 * SR];
    const int tid  = threadIdx.x;
    const int lane = tid & 63;
    const int wv   = tid >> 6;
    const int fg   = tid & 15;     // 16 feat groups x 8 cols
    const int rg   = tid >> 4;     // 16 row groups  x 4 rows
    const int row0 = blockIdx.x * 64;

    const int* off = (const int*)ws + WS_OFF;
    const int* ss  = (const int*)ws + WS_SORT;

    // ---- gather phase: wave wv owns rows [wv*16, wv*16+16) of the tile ----
    for (int ii = 0; ii < 16; ++ii) {
        const int i = wv * 16 + ii;
        const int r = row0 + i;
        float a0 = 0.f, a1 = 0.f;
        if (r < N_NODES) {
            a0 = x[(size_t)r * N_FEAT + lane];
            a1 = x[(size_t)r * N_FEAT + 64 + lane];
            const int lo = off[r], hi = off[r + 1];
            int e = lo;
            for (; e + 4 <= hi; e += 4) {
                int s0 = ss[e], s1 = ss[e + 1], s2 = ss[e + 2], s3 = ss[e + 3];
                const float* p0 = x + (size_t)s0 * N_FEAT;
                const float* p1 = x + (size_t)s1 * N_FEAT;
                const float* p2 = x + (size_t)s2 * N_FEAT;
                const float* p3 = x + (size_t)s3 * N_FEAT;
                float u0 = p0[lane], v0 = p0[64 + lane];
                float u1 = p1[lane], v1 = p1[64 + lane];
                float u2 = p2[lane], v2 = p2[64 + lane];
                float u3 = p3[lane], v3 = p3[64 + lane];
                a0 += u0 + u1 + u2 + u3;
                a1 += v0 + v1 + v2 + v3;
            }
            for (; e < hi; ++e) {
                const float* p = x + (size_t)ss[e] * N_FEAT;
                a0 += p[lane];
                a1 += p[64 + lane];
            }
        }
        As[i * SR + lane]      = a0;
        As[i * SR + 64 + lane] = a1;
    }
    __syncthreads();

    // ---- layer 1: acc = relu(As @ W1a + b1a), kept in registers ----------
    float acc[4][8];
    #pragma unroll
    for (int i = 0; i < 4; ++i)
        #pragma unroll
        for (int j = 0; j < 8; ++j) acc[i][j] = 0.f;

    #pragma unroll 2
    for (int k = 0; k < N_FEAT; k += 4) {
        float4 w[8];
        #pragma unroll
        for (int kk = 0; kk < 4; ++kk) {
            w[2 * kk]     = *(const float4*)(W1a + (k + kk) * N_FEAT + fg * 8);
            w[2 * kk + 1] = *(const float4*)(W1a + (k + kk) * N_FEAT + fg * 8 + 4);
        }
        #pragma unroll
        for (int i = 0; i < 4; ++i) {
            const float4 a4 = *(const float4*)(As + (rg * 4 + i) * SR + k);
            const float av[4] = {a4.x, a4.y, a4.z, a4.w};
            #pragma unroll
            for (int kk = 0; kk < 4; ++kk) {
                acc[i][0] += av[kk] * w[2 * kk].x;
                acc[i][1] += av[kk] * w[2 * kk].y;
                acc[i][2] += av[kk] * w[2 * kk].z;
                acc[i][3] += av[kk] * w[2 * kk].w;
                acc[i][4] += av[kk] * w[2 * kk + 1].x;
                acc[i][5] += av[kk] * w[2 * kk + 1].y;
                acc[i][6] += av[kk] * w[2 * kk + 1].z;
                acc[i][7] += av[kk] * w[2 * kk + 1].w;
            }
        }
    }
    __syncthreads();   // everyone done reading As before overwrite

    {
        const float4 ba0 = *(const float4*)(b1a + fg * 8);
        const float4 ba1 = *(const float4*)(b1a + fg * 8 + 4);
        #pragma unroll
        for (int i = 0; i < 4; ++i) {
            float4 u0, u1;
            u0.x = fmaxf(acc[i][0] + ba0.x, 0.f); u0.y = fmaxf(acc[i][1] + ba0.y, 0.f);
            u0.z = fmaxf(acc[i][2] + ba0.z, 0.f); u0.w = fmaxf(acc[i][3] + ba0.w, 0.f);
            u1.x = fmaxf(acc[i][4] + ba1.x, 0.f); u1.y = fmaxf(acc[i][5] + ba1.y, 0.f);
            u1.z = fmaxf(acc[i][6] + ba1.z, 0.f); u1.w = fmaxf(acc[i][7] + ba1.w, 0.f);
            *(float4*)(As + (rg * 4 + i) * SR + fg * 8)     = u0;
            *(float4*)(As + (rg * 4 + i) * SR + fg * 8 + 4) = u1;
        }
    }
    __syncthreads();

    // ---- layer 2: x1 = relu(As @ W1b + b1b) -> global buf -----------------
    #pragma unroll
    for (int i = 0; i < 4; ++i)
        #pragma unroll
        for (int j = 0; j < 8; ++j) acc[i][j] = 0.f;

    #pragma unroll 2
    for (int k = 0; k < N_FEAT; k += 4) {
        float4 w[8];
        #pragma unroll
        for (int kk = 0; kk < 4; ++kk) {
            w[2 * kk]     = *(const float4*)(W1b + (k + kk) * N_FEAT + fg * 8);
            w[2 * kk + 1] = *(const float4*)(W1b + (k + kk) * N_FEAT + fg * 8 + 4);
        }
        #pragma unroll
        for (int i = 0; i < 4; ++i) {
            const float4 a4 = *(const float4*)(As + (rg * 4 + i) * SR + k);
            const float av[4] = {a4.x, a4.y, a4.z, a4.w};
            #pragma unroll
            for (int kk = 0; kk < 4; ++kk) {
                acc[i][0] += av[kk] * w[2 * kk].x;
                acc[i][1] += av[kk] * w[2 * kk].y;
                acc[i][2] += av[kk] * w[2 * kk].z;
                acc[i][3] += av[kk] * w[2 * kk].w;
                acc[i][4] += av[kk] * w[2 * kk + 1].x;
                acc[i][5] += av[kk] * w[2 * kk + 1].y;
                acc[i][6] += av[kk] * w[2 * kk + 1].z;
                acc[i][7] += av[kk] * w[2 * kk + 1].w;
            }
        }
    }
    {
        float* __restrict__ buf = ws + WS_BUF;
        const float4 bb0 = *(const float4*)(b1b + fg * 8);
        const float4 bb1 = *(const float4*)(b1b + fg * 8 + 4);
        #pragma unroll
        for (int i = 0; i < 4; ++i) {
            int r = row0 + rg * 4 + i;
            if (r < N_NODES) {
                float4 u0, u1;
                u0.x = fmaxf(acc[i][0] + bb0.x, 0.f); u0.y = fmaxf(acc[i][1] + bb0.y, 0.f);
                u0.z = fmaxf(acc[i][2] + bb0.z, 0.f); u0.w = fmaxf(acc[i][3] + bb0.w, 0.f);
                u1.x = fmaxf(acc[i][4] + bb1.x, 0.f); u1.y = fmaxf(acc[i][5] + bb1.y, 0.f);
                u1.z = fmaxf(acc[i][6] + bb1.z, 0.f); u1.w = fmaxf(acc[i][7] + bb1.w, 0.f);
                *(float4*)(buf + (size_t)r * N_FEAT + fg * 8)     = u0;
                *(float4*)(buf + (size_t)r * N_FEAT + fg * 8 + 4) = u1;
            }
        }
    }
}

// --------- column sums / sums-of-squares of x1 (for BN batch stats) ---------
__global__ void k_stats(const float* __restrict__ buf, float* __restrict__ stats) {
    __shared__ float S[8][128];
    __shared__ float Q[8][128];
    const int tid = threadIdx.x;
    const int cg = tid & 31;
    const int rg = tid >> 5;
    float4 s = make_float4(0.f, 0.f, 0.f, 0.f);
    float4 q = make_float4(0.f, 0.f, 0.f, 0.f);
    for (int r = blockIdx.x * 8 + rg; r < N_NODES; r += gridDim.x * 8) {
        float4 v = *(const float4*)(buf + (size_t)r * N_FEAT + cg * 4);
        s.x += v.x; s.y += v.y; s.z += v.z; s.w += v.w;
        q.x += v.x * v.x; q.y += v.y * v.y; q.z += v.z * v.z; q.w += v.w * v.w;
    }
    S[rg][cg * 4 + 0] = s.x; S[rg][cg * 4 + 1] = s.y;
    S[rg][cg * 4 + 2] = s.z; S[rg][cg * 4 + 3] = s.w;
    Q[rg][cg * 4 + 0] = q.x; Q[rg][cg * 4 + 1] = q.y;
    Q[rg][cg * 4 + 2] = q.z; Q[rg][cg * 4 + 3] = q.w;
    __syncthreads();
    if (tid < 128) {
        float t = 0.f;
        #pragma unroll
        for (int g = 0; g < 8; ++g) t += S[g][tid];
        unsafeAtomicAdd(stats + tid, t);
    } else {
        int c = tid - 128;
        float t = 0.f;
        #pragma unroll
        for (int g = 0; g < 8; ++g) t += Q[g][c];
        unsafeAtomicAdd(stats + 128 + c, t);
    }
}

__global__ void k_finalize(const float* __restrict__ gamma, const float* __restrict__ beta,
                           float* __restrict__ ws) {
    int c = threadIdx.x;
    float mean = ws[WS_STATS + c] * (1.f / N_NODES);
    float var  = fmaxf(ws[WS_STATS + 128 + c] * (1.f / N_NODES) - mean * mean, 0.f);
    float sc = gamma[c] * rsqrtf(var + 1e-5f);
    ws[WS_SCALE + c] = sc;
    ws[WS_SCALE + 128 + c] = beta[c] - mean * sc;
}

__device__ __forceinline__ int lbound(const int* __restrict__ a, int n, int v) {
    int lo = 0, hi = n;
    while (lo < hi) { int m = (lo + hi) >> 1; if (a[m] < v) lo = m + 1; else hi = m; }
    return lo;
}

// --------- per-graph mean pool with BN applied on the fly -------------------
__global__ void k_pool(const float* __restrict__ buf, const int* __restrict__ batch,
                       float* __restrict__ ws) {
    __shared__ float S[8][128];
    __shared__ int range[2];
    const int g = blockIdx.x, tid = threadIdx.x;
    if (tid == 0) {
        range[0] = lbound(batch, N_NODES, g);
        range[1] = lbound(batch, N_NODES, g + 1);
    }
    __syncthreads();
    const int lo = range[0], hi = range[1];
    const int cg = tid & 31, rg = tid >> 5;
    float4 s = make_float4(0.f, 0.f, 0.f, 0.f);
    for (int r = lo + rg; r < hi; r += 8) {
        float4 v = *(const float4*)(buf + (size_t)r * N_FEAT + cg * 4);
        s.x += v.x; s.y += v.y; s.z += v.z; s.w += v.w;
    }
    S[rg][cg * 4 + 0] = s.x; S[rg][cg * 4 + 1] = s.y;
    S[rg][cg * 4 + 2] = s.z; S[rg][cg * 4 + 3] = s.w;
    __syncthreads();
    if (tid < 128) {
        float t = 0.f;
        #pragma unroll
        for (int g8 = 0; g8 < 8; ++g8) t += S[g8][tid];
        int cnt = hi - lo;
        float sc = ws[WS_SCALE + tid], sh = ws[WS_SCALE + 128 + tid];
        ws[WS_XG + g * N_FEAT + tid] = (cnt > 0) ? (sc * t / (float)cnt + sh) : 0.f;
    }
}

// --------- 10-iter gated recurrence + output MLP, block per graph -----------
__global__ __launch_bounds__(256) void k_recur(const float* __restrict__ ws,
        const float* __restrict__ Wl1, const float* __restrict__ bl1,
        const float* __restrict__ Wl2, const float* __restrict__ bl2,
        const float* __restrict__ Wm1, const float* __restrict__ bm1,
        const float* __restrict__ Wm2, const float* __restrict__ bm2,
        float* __restrict__ out) {
    __shared__ float W1h[128 * 64];
    __shared__ float W2h[128 * 64];
    __shared__ float xg_s[128];
    __shared__ float h_s[128];
    __shared__ float px[2][64];
    __shared__ float pq[2][2][64];
    __shared__ float m_s[DIMM];
    const int g = blockIdx.x, tid = threadIdx.x;

    for (int i = tid; i < 128 * 64; i += 256) {
        W1h[i] = Wl1[128 * 64 + i];
        W2h[i] = Wl2[128 * 64 + i];
    }
    if (tid < 128) {
        float v = ws[WS_XG + g * N_FEAT + tid];
        xg_s[tid] = v;
        h_s[tid] = v;
    }
    __syncthreads();

    const int sel  = tid >> 7;
    const int part = (tid >> 6) & 1;
    const int j    = tid & 63;

    {
        const float* Wg = sel ? Wl2 : Wl1;
        float a = 0.f;
        const int k0 = part * 64;
        #pragma unroll 4
        for (int k = 0; k < 64; ++k) a += xg_s[k0 + k] * Wg[(k0 + k) * 64 + j];
        pq[sel][part][j] = a;
    }
    __syncthreads();
    if (part == 0) {
        const float* bias = sel ? bl2 : bl1;
        px[sel][j] = pq[sel][0][j] + pq[sel][1][j] + bias[j];
    }
    __syncthreads();

    const float* Wh = sel ? W2h : W1h;
    for (int it = 0; it < N_ITERS; ++it) {
        float a = 0.f;
        const int k0 = part * 64;
        #pragma unroll
        for (int k = 0; k < 64; k += 4) {
            const float4 h4 = *(const float4*)(h_s + k0 + k);
            a += h4.x * Wh[(k0 + k + 0) * 64 + j];
            a += h4.y * Wh[(k0 + k + 1) * 64 + j];
            a += h4.z * Wh[(k0 + k + 2) * 64 + j];
            a += h4.w * Wh[(k0 + k + 3) * 64 + j];
        }
        pq[sel][part][j] = a;
        __syncthreads();
        if (part == 0) {
            float tot = pq[sel][0][j] + pq[sel][1][j] + px[sel][j];
            if (sel == 0) h_s[64 + j] = 1.f / (1.f + expf(-tot));
            else          h_s[j] = tanhf(tot);
        }
        __syncthreads();
    }

    if (tid < DIMM) {
        float a = bm1[tid];
        #pragma unroll 4
        for (int k = 0; k < 128; ++k) a += h_s[k] * Wm1[k * DIMM + tid];
        m_s[tid] = fmaxf(a, 0.f);
    }
    __syncthreads();
    if (tid < N_OUTD) {
        float a = bm2[tid];
        for (int k = 0; k < DIMM; ++k) a += m_s[k] * Wm2[k * N_OUTD + tid];
        out[g * N_OUTD + tid] = a;
    }
}

extern "C" void kernel_launch(void* const* d_in, const int* in_sizes, int n_in,
                              void* d_out, int out_size, void* d_ws, size_t ws_size,
                              hipStream_t stream) {
    const float* x     = (const float*)d_in[0];
    const int*   ei    = (const int*)d_in[1];
    const int*   batch = (const int*)d_in[2];
    const float* W1a = (const float*)d_in[3];
    const float* b1a = (const float*)d_in[4];
    const float* W1b = (const float*)d_in[5];
    const float* b1b = (const float*)d_in[6];
    const float* gamma = (const float*)d_in[7];
    const float* beta  = (const float*)d_in[8];
    const float* Wl1 = (const float*)d_in[9];
    const float* bl1 = (const float*)d_in[10];
    const float* Wl2 = (const float*)d_in[11];
    const float* bl2 = (const float*)d_in[12];
    const float* Wm1 = (const float*)d_in[13];
    const float* bm1 = (const float*)d_in[14];
    const float* Wm2 = (const float*)d_in[15];
    const float* bm2 = (const float*)d_in[16];
    float* out = (float*)d_out;
    float* ws  = (float*)d_ws;

    k_zero   <<<(N_NODES + 255) / 256, 256, 0, stream>>>(ws);
    k_hist   <<<(N_EDGES + 255) / 256, 256, 0, stream>>>(ei, ws);
    k_chunk  <<<N_CHUNKS, 256, 0, stream>>>(ws);
    k_scan0  <<<1, 256, 0, stream>>>(ws);
    k_scan1  <<<N_CHUNKS, 256, 0, stream>>>(ws);
    k_scatter<<<(N_EDGES + 255) / 256, 256, 0, stream>>>(ei, ws);
    k_fused  <<<(N_NODES + 63) / 64, 256, 0, stream>>>(x, ws, W1a, b1a, W1b, b1b);
    k_stats  <<<512, 256, 0, stream>>>(ws + WS_BUF, ws + WS_STATS);
    k_finalize<<<1, 128, 0, stream>>>(gamma, beta, ws);
    k_pool   <<<N_GRAPHS, 256, 0, stream>>>(ws + WS_BUF, batch, ws);
    k_recur  <<<N_GRAPHS, 256, 0, stream>>>(ws, Wl1, bl1, Wl2, bl2, Wm1, bm1, Wm2, bm2, out);
}

// Round 5
// 311.891 us; speedup vs baseline: 1.0973x; 1.0973x over previous
//
#include <hip/hip_runtime.h>
#include <cstddef>

#define N_NODES  50000
#define N_EDGES  600000
#define N_FEAT   128
#define N_GRAPHS 256
#define DIMM     95
#define N_OUTD   12
#define N_ITERS  10

#define N_CHUNKS 196          // ceil(50000/256)

// workspace layout (float-element offsets; int arrays reinterpret the region)
#define WS_STATS 0                        // [256] colsum[128], colsumsq[128]
#define WS_XG    (WS_STATS + 256)         // [256*128] raw pooled sums -> xg
#define WS_CNT   (WS_XG + N_GRAPHS * N_FEAT)   // int[50000] per-node degree
#define WS_OFF   (WS_CNT + N_NODES)            // int[50001] CSR offsets (pad 50004)
#define WS_CUR   (WS_OFF + N_NODES + 4)        // int[50000] scatter cursors
#define WS_CHS   (WS_CUR + N_NODES)            // int[256] chunk sums
#define WS_SORT  (WS_CHS + 256)                // int[600000] src sorted by dst

#define SR 132   // padded LDS row stride (128+4)

// ---- zero degree counters + BN stats + pooled sums -------------------------
__global__ void k_zero(float* __restrict__ ws) {
    int i = blockIdx.x * 256 + threadIdx.x;
    int* cnt = (int*)ws + WS_CNT;
    if (i < N_NODES) cnt[i] = 0;
    if (i < 256) ws[WS_STATS + i] = 0.f;
    if (i < N_GRAPHS * N_FEAT) ws[WS_XG + i] = 0.f;
}

// ---- degree histogram ------------------------------------------------------
__global__ void k_hist(const int* __restrict__ ei, float* __restrict__ ws) {
    int e = blockIdx.x * 256 + threadIdx.x;
    int* cnt = (int*)ws + WS_CNT;
    if (e < N_EDGES) atomicAdd(&cnt[ei[N_EDGES + e]], 1);
}

// ---- per-chunk sums (chunk = 256 nodes) ------------------------------------
__global__ void k_chunk(float* __restrict__ ws) {
    __shared__ int red[4];
    const int tid = threadIdx.x;
    int* cnt = (int*)ws + WS_CNT;
    int i = blockIdx.x * 256 + tid;
    int v = (i < N_NODES) ? cnt[i] : 0;
    #pragma unroll
    for (int d = 32; d; d >>= 1) v += __shfl_down(v, d);
    if ((tid & 63) == 0) red[tid >> 6] = v;
    __syncthreads();
    if (tid == 0) ((int*)ws + WS_CHS)[blockIdx.x] = red[0] + red[1] + red[2] + red[3];
}

// ---- exclusive scan of the (<=256) chunk sums, single block ----------------
__global__ void k_scan0(float* __restrict__ ws) {
    __shared__ int s[256];
    const int tid = threadIdx.x;
    int* chs = (int*)ws + WS_CHS;
    int v = (tid < N_CHUNKS) ? chs[tid] : 0;
    s[tid] = v;
    __syncthreads();
    #pragma unroll
    for (int d = 1; d < 256; d <<= 1) {
        int t = (tid >= d) ? s[tid - d] : 0;
        __syncthreads();
        s[tid] += t;
        __syncthreads();
    }
    if (tid < N_CHUNKS) chs[tid] = s[tid] - v;            // exclusive
    if (tid == 0) ((int*)ws + WS_OFF)[N_NODES] = N_EDGES; // sentinel
}

// ---- per-chunk exclusive scan -> CSR offsets + cursor copy -----------------
__global__ void k_scan1(float* __restrict__ ws) {
    __shared__ int s[256];
    const int tid = threadIdx.x;
    int* cnt = (int*)ws + WS_CNT;
    int* off = (int*)ws + WS_OFF;
    int* cur = (int*)ws + WS_CUR;
    int i = blockIdx.x * 256 + tid;
    int v = (i < N_NODES) ? cnt[i] : 0;
    s[tid] = v;
    __syncthreads();
    #pragma unroll
    for (int d = 1; d < 256; d <<= 1) {
        int t = (tid >= d) ? s[tid - d] : 0;
        __syncthreads();
        s[tid] += t;
        __syncthreads();
    }
    int o = ((int*)ws + WS_CHS)[blockIdx.x] + s[tid] - v;
    if (i < N_NODES) { off[i] = o; cur[i] = o; }
}

// ---- scatter: sortedSrc[pos in dst segment] = src --------------------------
__global__ void k_scatter(const int* __restrict__ ei, float* __restrict__ ws) {
    int e = blockIdx.x * 256 + threadIdx.x;
    if (e >= N_EDGES) return;
    int d = ei[N_EDGES + e];
    int s = ei[e];
    int* cur = (int*)ws + WS_CUR;
    int pos = atomicAdd(&cur[d], 1);
    ((int*)ws + WS_SORT)[pos] = s;
}

// ---- fused: CSR gather + 2-layer MLP + BN-stats partials + pool partials ---
// x1 never touches global memory: tile lives in LDS; stats and raw pooled
// sums leave via per-block atomics. 35 KB LDS -> 4 blocks/CU.
__global__ __launch_bounds__(256, 4) void k_fused(const float* __restrict__ x,
        const int* __restrict__ batch, float* __restrict__ ws,
        const float* __restrict__ W1a, const float* __restrict__ b1a,
        const float* __restrict__ W1b, const float* __restrict__ b1b) {
    __shared__ float As[64 * SR];
    __shared__ float red[256];
    __shared__ int batch_l[64];
    const int tid  = threadIdx.x;
    const int lane = tid & 63;
    const int wv   = tid >> 6;
    const int fg   = tid & 15;     // 16 feat groups x 8 cols
    const int rg   = tid >> 4;     // 16 row groups  x 4 rows
    const int row0 = blockIdx.x * 64;

    const int* off = (const int*)ws + WS_OFF;
    const int* ss  = (const int*)ws + WS_SORT;

    if (tid < 64) {
        int r = row0 + tid;
        batch_l[tid] = (r < N_NODES) ? batch[r] : (N_GRAPHS - 1);
    }

    // ---- gather: wave wv owns rows [wv*16, wv*16+16); lane covers cols
    // 2*lane, 2*lane+1 so ONE float2 load grabs a whole 512B row per wave.
    for (int ii = 0; ii < 16; ++ii) {
        const int i = wv * 16 + ii;
        const int r = row0 + i;
        float2 acc = make_float2(0.f, 0.f);
        if (r < N_NODES) {
            acc = *(const float2*)(x + (size_t)r * N_FEAT + 2 * lane);
            const int lo = off[r], hi = off[r + 1];
            for (int c0 = lo; c0 < hi; c0 += 64) {
                const int cdeg = min(64, hi - c0);
                int myidx = (lane < cdeg) ? ss[c0 + lane] : 0;  // one coalesced load
                int j = 0;
                for (; j + 4 <= cdeg; j += 4) {
                    int s0 = __shfl(myidx, j);
                    int s1 = __shfl(myidx, j + 1);
                    int s2 = __shfl(myidx, j + 2);
                    int s3 = __shfl(myidx, j + 3);
                    float2 v0 = *(const float2*)(x + (size_t)s0 * N_FEAT + 2 * lane);
                    float2 v1 = *(const float2*)(x + (size_t)s1 * N_FEAT + 2 * lane);
                    float2 v2 = *(const float2*)(x + (size_t)s2 * N_FEAT + 2 * lane);
                    float2 v3 = *(const float2*)(x + (size_t)s3 * N_FEAT + 2 * lane);
                    acc.x += v0.x + v1.x + v2.x + v3.x;
                    acc.y += v0.y + v1.y + v2.y + v3.y;
                }
                for (; j < cdeg; ++j) {
                    int s = __shfl(myidx, j);
                    float2 v = *(const float2*)(x + (size_t)s * N_FEAT + 2 * lane);
                    acc.x += v.x; acc.y += v.y;
                }
            }
        }
        *(float2*)(As + i * SR + 2 * lane) = acc;
    }
    __syncthreads();

    // ---- layer 1: acc = relu(As @ W1a + b1a), kept in registers ----------
    float acc[4][8];
    #pragma unroll
    for (int i = 0; i < 4; ++i)
        #pragma unroll
        for (int j = 0; j < 8; ++j) acc[i][j] = 0.f;

    #pragma unroll 2
    for (int k = 0; k < N_FEAT; k += 4) {
        float4 w[8];
        #pragma unroll
        for (int kk = 0; kk < 4; ++kk) {
            w[2 * kk]     = *(const float4*)(W1a + (k + kk) * N_FEAT + fg * 8);
            w[2 * kk + 1] = *(const float4*)(W1a + (k + kk) * N_FEAT + fg * 8 + 4);
        }
        #pragma unroll
        for (int i = 0; i < 4; ++i) {
            const float4 a4 = *(const float4*)(As + (rg * 4 + i) * SR + k);
            const float av[4] = {a4.x, a4.y, a4.z, a4.w};
            #pragma unroll
            for (int kk = 0; kk < 4; ++kk) {
                acc[i][0] += av[kk] * w[2 * kk].x;
                acc[i][1] += av[kk] * w[2 * kk].y;
                acc[i][2] += av[kk] * w[2 * kk].z;
                acc[i][3] += av[kk] * w[2 * kk].w;
                acc[i][4] += av[kk] * w[2 * kk + 1].x;
                acc[i][5] += av[kk] * w[2 * kk + 1].y;
                acc[i][6] += av[kk] * w[2 * kk + 1].z;
                acc[i][7] += av[kk] * w[2 * kk + 1].w;
            }
        }
    }
    __syncthreads();   // everyone done reading As before overwrite

    {
        const float4 ba0 = *(const float4*)(b1a + fg * 8);
        const float4 ba1 = *(const float4*)(b1a + fg * 8 + 4);
        #pragma unroll
        for (int i = 0; i < 4; ++i) {
            float4 u0, u1;
            u0.x = fmaxf(acc[i][0] + ba0.x, 0.f); u0.y = fmaxf(acc[i][1] + ba0.y, 0.f);
            u0.z = fmaxf(acc[i][2] + ba0.z, 0.f); u0.w = fmaxf(acc[i][3] + ba0.w, 0.f);
            u1.x = fmaxf(acc[i][4] + ba1.x, 0.f); u1.y = fmaxf(acc[i][5] + ba1.y, 0.f);
            u1.z = fmaxf(acc[i][6] + ba1.z, 0.f); u1.w = fmaxf(acc[i][7] + ba1.w, 0.f);
            *(float4*)(As + (rg * 4 + i) * SR + fg * 8)     = u0;
            *(float4*)(As + (rg * 4 + i) * SR + fg * 8 + 4) = u1;
        }
    }
    __syncthreads();

    // ---- layer 2: x1 = relu(As @ W1b + b1b) -> back into As ---------------
    #pragma unroll
    for (int i = 0; i < 4; ++i)
        #pragma unroll
        for (int j = 0; j < 8; ++j) acc[i][j] = 0.f;

    #pragma unroll 2
    for (int k = 0; k < N_FEAT; k += 4) {
        float4 w[8];
        #pragma unroll
        for (int kk = 0; kk < 4; ++kk) {
            w[2 * kk]     = *(const float4*)(W1b + (k + kk) * N_FEAT + fg * 8);
            w[2 * kk + 1] = *(const float4*)(W1b + (k + kk) * N_FEAT + fg * 8 + 4);
        }
        #pragma unroll
        for (int i = 0; i < 4; ++i) {
            const float4 a4 = *(const float4*)(As + (rg * 4 + i) * SR + k);
            const float av[4] = {a4.x, a4.y, a4.z, a4.w};
            #pragma unroll
            for (int kk = 0; kk < 4; ++kk) {
                acc[i][0] += av[kk] * w[2 * kk].x;
                acc[i][1] += av[kk] * w[2 * kk].y;
                acc[i][2] += av[kk] * w[2 * kk].z;
                acc[i][3] += av[kk] * w[2 * kk].w;
                acc[i][4] += av[kk] * w[2 * kk + 1].x;
                acc[i][5] += av[kk] * w[2 * kk + 1].y;
                acc[i][6] += av[kk] * w[2 * kk + 1].z;
                acc[i][7] += av[kk] * w[2 * kk + 1].w;
            }
        }
    }
    __syncthreads();   // done reading layer-1 As before overwrite with x1

    {
        const float4 bb0 = *(const float4*)(b1b + fg * 8);
        const float4 bb1 = *(const float4*)(b1b + fg * 8 + 4);
        #pragma unroll
        for (int i = 0; i < 4; ++i) {
            float4 u0, u1;
            u0.x = fmaxf(acc[i][0] + bb0.x, 0.f); u0.y = fmaxf(acc[i][1] + bb0.y, 0.f);
            u0.z = fmaxf(acc[i][2] + bb0.z, 0.f); u0.w = fmaxf(acc[i][3] + bb0.w, 0.f);
            u1.x = fmaxf(acc[i][4] + bb1.x, 0.f); u1.y = fmaxf(acc[i][5] + bb1.y, 0.f);
            u1.z = fmaxf(acc[i][6] + bb1.z, 0.f); u1.w = fmaxf(acc[i][7] + bb1.w, 0.f);
            *(float4*)(As + (rg * 4 + i) * SR + fg * 8)     = u0;
            *(float4*)(As + (rg * 4 + i) * SR + fg * 8 + 4) = u1;
        }
    }
    __syncthreads();

    // ---- epilogue: BN-stat partials + raw pooled-sum partials -------------
    // thread t: col c = t&127, half h = t>>7 (local rows h*32 .. h*32+31).
    {
        const int c = tid & 127;
        const int h = tid >> 7;
        float sum = 0.f, sq = 0.f, pool = 0.f;
        int curg = batch_l[h * 32];
        bool any = (row0 + h * 32) < N_NODES;
        #pragma unroll 4
        for (int rr = 0; rr < 32; ++rr) {
            int rl = h * 32 + rr;
            if (row0 + rl >= N_NODES) break;
            float v = As[rl * SR + c];
            int g = batch_l[rl];
            if (g != curg) {   // wave-uniform branch (same rows across lanes)
                unsafeAtomicAdd(ws + WS_XG + (size_t)curg * N_FEAT + c, pool);
                pool = 0.f; curg = g;
            }
            sum += v; sq += v * v; pool += v;
        }
        if (any) unsafeAtomicAdd(ws + WS_XG + (size_t)curg * N_FEAT + c, pool);
        if (h == 1) { red[c] = sum; red[128 + c] = sq; }
        __syncthreads();
        if (h == 0) {
            unsafeAtomicAdd(ws + WS_STATS + c, sum + red[c]);
            unsafeAtomicAdd(ws + WS_STATS + 128 + c, sq + red[128 + c]);
        }
    }
}

__device__ __forceinline__ int lbound(const int* __restrict__ a, int n, int v) {
    int lo = 0, hi = n;
    while (lo < hi) { int m = (lo + hi) >> 1; if (a[m] < v) lo = m + 1; else hi = m; }
    return lo;
}

// ---- apply BN scale/shift + mean division to pooled sums (in place) --------
// BN then mean-pool == scale*(poolsum/cnt) + shift  (affine commutes w/ mean)
__global__ void k_apply(const int* __restrict__ batch,
                        const float* __restrict__ gamma, const float* __restrict__ beta,
                        float* __restrict__ ws) {
    const int g = blockIdx.x, c = threadIdx.x;   // 128 threads
    __shared__ int range[2];
    if (c < 2) range[c] = lbound(batch, N_NODES, g + c);
    __syncthreads();
    const int cnt = range[1] - range[0];
    float mean = ws[WS_STATS + c] * (1.f / N_NODES);
    float var  = fmaxf(ws[WS_STATS + 128 + c] * (1.f / N_NODES) - mean * mean, 0.f);
    float sc = gamma[c] * rsqrtf(var + 1e-5f);
    float sh = beta[c] - mean * sc;
    float pool = ws[WS_XG + (size_t)g * N_FEAT + c];
    ws[WS_XG + (size_t)g * N_FEAT + c] = (cnt > 0) ? (sc * pool / (float)cnt + sh) : 0.f;
}

// --------- 10-iter gated recurrence + output MLP, block per graph -----------
__global__ __launch_bounds__(256) void k_recur(const float* __restrict__ ws,
        const float* __restrict__ Wl1, const float* __restrict__ bl1,
        const float* __restrict__ Wl2, const float* __restrict__ bl2,
        const float* __restrict__ Wm1, const float* __restrict__ bm1,
        const float* __restrict__ Wm2, const float* __restrict__ bm2,
        float* __restrict__ out) {
    __shared__ float W1h[128 * 64];
    __shared__ float W2h[128 * 64];
    __shared__ float xg_s[128];
    __shared__ float h_s[128];
    __shared__ float px[2][64];
    __shared__ float pq[2][2][64];
    __shared__ float m_s[DIMM];
    const int g = blockIdx.x, tid = threadIdx.x;

    for (int i = tid; i < 128 * 64; i += 256) {
        W1h[i] = Wl1[128 * 64 + i];
        W2h[i] = Wl2[128 * 64 + i];
    }
    if (tid < 128) {
        float v = ws[WS_XG + g * N_FEAT + tid];
        xg_s[tid] = v;
        h_s[tid] = v;
    }
    __syncthreads();

    const int sel  = tid >> 7;
    const int part = (tid >> 6) & 1;
    const int j    = tid & 63;

    {
        const float* Wg = sel ? Wl2 : Wl1;
        float a = 0.f;
        const int k0 = part * 64;
        #pragma unroll 4
        for (int k = 0; k < 64; ++k) a += xg_s[k0 + k] * Wg[(k0 + k) * 64 + j];
        pq[sel][part][j] = a;
    }
    __syncthreads();
    if (part == 0) {
        const float* bias = sel ? bl2 : bl1;
        px[sel][j] = pq[sel][0][j] + pq[sel][1][j] + bias[j];
    }
    __syncthreads();

    const float* Wh = sel ? W2h : W1h;
    for (int it = 0; it < N_ITERS; ++it) {
        float a = 0.f;
        const int k0 = part * 64;
        #pragma unroll
        for (int k = 0; k < 64; k += 4) {
            const float4 h4 = *(const float4*)(h_s + k0 + k);
            a += h4.x * Wh[(k0 + k + 0) * 64 + j];
            a += h4.y * Wh[(k0 + k + 1) * 64 + j];
            a += h4.z * Wh[(k0 + k + 2) * 64 + j];
            a += h4.w * Wh[(k0 + k + 3) * 64 + j];
        }
        pq[sel][part][j] = a;
        __syncthreads();
        if (part == 0) {
            float tot = pq[sel][0][j] + pq[sel][1][j] + px[sel][j];
            if (sel == 0) h_s[64 + j] = 1.f / (1.f + expf(-tot));
            else          h_s[j] = tanhf(tot);
        }
        __syncthreads();
    }

    if (tid < DIMM) {
        float a = bm1[tid];
        #pragma unroll 4
        for (int k = 0; k < 128; ++k) a += h_s[k] * Wm1[k * DIMM + tid];
        m_s[tid] = fmaxf(a, 0.f);
    }
    __syncthreads();
    if (tid < N_OUTD) {
        float a = bm2[tid];
        for (int k = 0; k < DIMM; ++k) a += m_s[k] * Wm2[k * N_OUTD + tid];
        out[g * N_OUTD + tid] = a;
    }
}

extern "C" void kernel_launch(void* const* d_in, const int* in_sizes, int n_in,
                              void* d_out, int out_size, void* d_ws, size_t ws_size,
                              hipStream_t stream) {
    const float* x     = (const float*)d_in[0];
    const int*   ei    = (const int*)d_in[1];
    const int*   batch = (const int*)d_in[2];
    const float* W1a = (const float*)d_in[3];
    const float* b1a = (const float*)d_in[4];
    const float* W1b = (const float*)d_in[5];
    const float* b1b = (const float*)d_in[6];
    const float* gamma = (const float*)d_in[7];
    const float* beta  = (const float*)d_in[8];
    const float* Wl1 = (const float*)d_in[9];
    const float* bl1 = (const float*)d_in[10];
    const float* Wl2 = (const float*)d_in[11];
    const float* bl2 = (const float*)d_in[12];
    const float* Wm1 = (const float*)d_in[13];
    const float* bm1 = (const float*)d_in[14];
    const float* Wm2 = (const float*)d_in[15];
    const float* bm2 = (const float*)d_in[16];
    float* out = (float*)d_out;
    float* ws  = (float*)d_ws;

    k_zero   <<<(N_NODES + 255) / 256, 256, 0, stream>>>(ws);
    k_hist   <<<(N_EDGES + 255) / 256, 256, 0, stream>>>(ei, ws);
    k_chunk  <<<N_CHUNKS, 256, 0, stream>>>(ws);
    k_scan0  <<<1, 256, 0, stream>>>(ws);
    k_scan1  <<<N_CHUNKS, 256, 0, stream>>>(ws);
    k_scatter<<<(N_EDGES + 255) / 256, 256, 0, stream>>>(ei, ws);
    k_fused  <<<(N_NODES + 63) / 64, 256, 0, stream>>>(x, batch, ws, W1a, b1a, W1b, b1b);
    k_apply  <<<N_GRAPHS, 128, 0, stream>>>(batch, gamma, beta, ws);
    k_recur  <<<N_GRAPHS, 256, 0, stream>>>(ws, Wl1, bl1, Wl2, bl2, Wm1, bm1, Wm2, bm2, out);
}